// Round 7
// baseline (3998.794 us; speedup 1.0000x reference)
//
#include <hip/hip_runtime.h>
#include <hip/hip_bf16.h>

// GRU last-hidden: B=64, T=512, I=256, H=512, fp32 in/out.
//
// Round-12: XCD-LOCAL exchange, replay-safe, self-verified.
// R11 post-mortem: fast path demoted immediately (plain cached loads serve
// the consumer's own stale L2; sc1 stores do NOT invalidate remote-XCD L2
// copies) -> cross-XCD cached consumption is falsified. R9/R10's one-XCD
// plan was never actually tested: their vote read stale monotone ws state
// (ws persists across launches - proven by R11's all-zero signature).
// This round:
//  * NO vote. 512 blocks exact-fill (2 WG/CU, launch_bounds(256,2); R9's
//    completion proves 512 co-residency). Workers = blocks bid%8==0 which
//    under the CP's round-robin block->XCD mapping share ONE XCD; rank =
//    bid>>3. The mapping is NOT assumed:
//  * 3-phase coherence SELF-TEST (timestamp barriers, epoch-tagged magic
//    so replayed ws content can never false-pass): arm own L1/L2 with the
//    test lines -> peer plain-store magic + vmcnt drain (reaches only the
//    producer's XCD L2) -> buffer_inv sc0 + plain re-read. Seeing all 64
//    fresh magics proves {one shared L2 + working L1 invalidate}. Any
//    mismatch -> ALL demote to the R5-proven sc1/L3 protocol.
//  * ALL sync is timestamp-based (s_memrealtime vs kernel-entry t0):
//    stale ws values are always < this launch's t0. No ws-zeroing
//    assumption anywhere. 2ms deadline on the 512-flag barrier degrades
//    to R5's (empirically safe) weak barrier instead of hanging.
//  * Worker loop = UNCHANGED R5 protocol; only the medium differs:
//    FAST = plain stores (write-through into shared XCD L2) + buffer_inv
//    sc0 + plain loads; CLASSIC = sc1 everything (R5 exactly).

#define NB 64
#define NT 512
#define NI 256
#define NH 512

// ws layout (no content assumptions; all gating is timestamp-based):
#define OFF_FLAGS   0u        // u64[512], stride 64B  [0,32K)
#define OFF_TSB1    32768u    // u64[64] stride 64B (self-test barrier 1)
#define OFF_TSB2    36864u    // barrier 2
#define OFF_TSB3    40960u    // barrier 3
#define OFF_DEMOTE  45056u    // u64 timestamp marker
#define OFF_TESTA   49152u    // 64 test slots, stride 64B [49152,53248)
#define OFF_TAGS    57344u    // int[4][64]
#define OFF_HB0     65536u    // 64KB h buffer (parity 0)
#define OFF_HB1     131072u   // 64KB h buffer (parity 1)
#define OFF_XB      262144u   // x as bf16 [b][t][i], 16MB

typedef __attribute__((ext_vector_type(8))) short bf16x8;
typedef __attribute__((ext_vector_type(4))) float f32x4;
typedef __attribute__((ext_vector_type(4))) int i32x4;

static __device__ __forceinline__ short f2b(float f) {
  unsigned u = __builtin_bit_cast(unsigned, f);
  unsigned r = (u + 0x7fffu + ((u >> 16) & 1u)) >> 16;
  return (short)r;
}
static __device__ __forceinline__ float sigm(float x) {
  return 1.0f / (1.0f + __expf(-x));
}
static __device__ __forceinline__ float tanh_f(float x) {
  return 1.0f - 2.0f / (__expf(2.0f * x) + 1.0f);
}

// timestamp barrier among the 64 workers (one slot array per phase; a
// fresh write is always >= every worker's kernel-entry t0 because phase
// writes happen after the 512-flag barrier, whose flags postdate all
// entries; stale values from a previous launch are always < t0).
static __device__ __forceinline__ void tsbar(unsigned char* base, int rank,
                                             int tid, int wave, int lane,
                                             unsigned long long t0) {
  __syncthreads();
  if (tid == 0)
    __hip_atomic_store((unsigned long long*)(base + (size_t)rank * 64),
                       __builtin_amdgcn_s_memrealtime(), __ATOMIC_RELEASE,
                       __HIP_MEMORY_SCOPE_AGENT);
  if (wave == 0) {
    while (__hip_atomic_load(
               (const unsigned long long*)(base + (size_t)lane * 64),
               __ATOMIC_RELAXED, __HIP_MEMORY_SCOPE_AGENT) < t0)
      __builtin_amdgcn_s_sleep(1);
  }
  __syncthreads();
  __threadfence();
}

// 16 coalesced 16B loads of the full h fragment set.
#define LOAD_ALL(FLAG)                                                        \
  do {                                                                        \
    const char* hbase_ = (const char*)hcur;                                   \
    _Pragma("unroll") for (int kk2 = 0; kk2 < 16; kk2++) {                    \
      const void* ap_ = hbase_ + (size_t)(((kk2 * 4 + q) * 64 + b0) << 4);    \
      asm volatile("global_load_dwordx4 %0, %1, off " FLAG                    \
                   : "=v"(hv[kk2]) : "v"(ap_));                               \
    }                                                                         \
  } while (0)

#define WAIT_ALL()                                                            \
  asm volatile("s_waitcnt vmcnt(0)"                                           \
               : "+v"(hv[0]), "+v"(hv[1]), "+v"(hv[2]), "+v"(hv[3]),          \
                 "+v"(hv[4]), "+v"(hv[5]), "+v"(hv[6]), "+v"(hv[7]),          \
                 "+v"(hv[8]), "+v"(hv[9]), "+v"(hv[10]), "+v"(hv[11]),        \
                 "+v"(hv[12]), "+v"(hv[13]), "+v"(hv[14]), "+v"(hv[15])       \
               ::"memory")

template <bool FAST>
static __device__ __forceinline__ void worker_body(
    int wg, int tid, const float* __restrict__ bih,
    const float* __restrict__ bhh, float* __restrict__ out,
    unsigned char* __restrict__ ws, const bf16x8 wh[2][16],
    const bf16x8 wi[2][8], unsigned short (*trans)[16][8]) {
  const int wave = tid >> 6;
  const int lane = tid & 63;
  const int c    = lane & 15;
  const int q    = lane >> 4;

  int* tags = (int*)(ws + OFF_TAGS);
  unsigned short* hb0 = (unsigned short*)(ws + OFF_HB0);
  unsigned short* hb1 = (unsigned short*)(ws + OFF_HB1);
  const unsigned short* xb = (const unsigned short*)(ws + OFF_XB);

  const int jcol = wg * 8 + (c & 7);
  const float bri = bih[jcol],          brh = bhh[jcol];
  const float bzi = bih[NH + jcol],     bzh = bhh[NH + jcol];
  const float bni = bih[2 * NH + jcol], bnh = bhh[2 * NH + jcol];

  float hold[4] = {0.f, 0.f, 0.f, 0.f};  // fp32 master state (c<8 lanes)

  const int b0 = wave * 16 + c;
  int* mytags = tags + wave * 64;
  const int* tagp = mytags + lane;

  for (int t = 0; t < NT; t++) {
    const unsigned short* hcur = (t & 1) ? hb1 : hb0;
    unsigned short* hnext      = (t & 1) ? hb0 : hb1;

    f32x4 aX0 = {0.f,0.f,0.f,0.f}, aX1 = {0.f,0.f,0.f,0.f};
    f32x4 aH0 = {0.f,0.f,0.f,0.f}, aH1 = {0.f,0.f,0.f,0.f};

    const bf16x8* xr = (const bf16x8*)(xb + ((size_t)b0 * NT + t) * NI);

    // x-projection (cached; fills wall clock while producers publish)
#pragma unroll
    for (int kk = 0; kk < 8; kk++) {
      bf16x8 a = xr[kk * 4 + q];
      aX0 = __builtin_amdgcn_mfma_f32_16x16x32_bf16(a, wi[0][kk], aX0, 0,0,0);
      aX1 = __builtin_amdgcn_mfma_f32_16x16x32_bf16(a, wi[1][kk], aX1, 0,0,0);
    }

    // poll for h_t (tags >= t+1). FAST: L1 invalidate + plain load (hits
    // the shared XCD L2, ~300cy); CLASSIC: sc1 (L3, R5-proven). The
    // successful FAST iteration's inv also cleans stale h-data lines; no
    // h-address is touched between that inv and the data loads, and any
    // line the co-CU worker re-installs is post-its-own-inv (L2-fresh).
    if (t > 0) {
      const int need = t + 1;
      if (FAST) {
        for (;;) {
          asm volatile("buffer_inv sc0" ::: "memory");
          int v;
          asm volatile("global_load_dword %0, %1, off" : "=v"(v) : "v"(tagp));
          asm volatile("s_waitcnt vmcnt(0)" : "+v"(v)::"memory");
          if (__all(v >= need)) break;
        }
      } else {
        for (;;) {
          int v;
          asm volatile("global_load_dword %0, %1, off sc1"
                       : "=v"(v) : "v"(tagp));
          asm volatile("s_waitcnt vmcnt(0)" : "+v"(v)::"memory");
          if (__all(v >= need)) break;
        }
      }
    } else if (FAST) {
      asm volatile("buffer_inv sc0" ::: "memory");  // belt & braces at t=0
    }

    i32x4 hv[16];
    if (FAST) LOAD_ALL(""); else LOAD_ALL("sc1");
    WAIT_ALL();

    // h-projection
#pragma unroll
    for (int kk = 0; kk < 16; kk++) {
      bf16x8 a = __builtin_bit_cast(bf16x8, hv[kk]);
      aH0 = __builtin_amdgcn_mfma_f32_16x16x32_bf16(a, wh[0][kk], aH0, 0,0,0);
      aH1 = __builtin_amdgcn_mfma_f32_16x16x32_bf16(a, wh[1][kk], aH1, 0,0,0);
    }

    // epilogue: C/D layout col=lane&15, row=q*4+reg. Lane c<8 owns col wg*8+c.
#pragma unroll
    for (int r = 0; r < 4; r++) {
      float xz = __shfl_xor(aX0[r], 8, 64);
      float hz = __shfl_xor(aH0[r], 8, 64);
      float rr = sigm(aX0[r] + bri + aH0[r] + brh);
      float zz = sigm(xz + bzi + hz + bzh);
      float nn = tanh_f(aX1[r] + bni + rr * (aH1[r] + bnh));
      float hv2 = (1.0f - zz) * nn + zz * hold[r];
      hold[r] = hv2;
      if (c < 8) trans[wave][q * 4 + r][c] = (unsigned short)f2b(hv2);
    }

    if (t < NT - 1) {
      // publish: LDS transpose -> 16B stores; drain (FAST: L2 ack ~300cy,
      // CLASSIC: L3). vmcnt(0) also covers this wave's step-t h loads ->
      // tag >= t+2 certifies overwrite safety (R5 induction, unchanged).
      asm volatile("s_waitcnt lgkmcnt(0)" ::: "memory");
      if (lane < 16) {
        int b = wave * 16 + lane;
        i32x4 pk = *(const i32x4*)&trans[wave][lane][0];
        void* dst = (char*)hnext + ((size_t)(wg * 64 + b) << 4);
        if (FAST)
          asm volatile("global_store_dwordx4 %0, %1, off"
                       :: "v"(dst), "v"(pk) : "memory");
        else
          asm volatile("global_store_dwordx4 %0, %1, off sc1"
                       :: "v"(dst), "v"(pk) : "memory");
      }
      asm volatile("s_waitcnt vmcnt(0)" ::: "memory");
      if (lane == 0) {
        int* tp = &mytags[wg];
        int tv = t + 2;
        if (FAST)
          asm volatile("global_store_dword %0, %1, off"
                       :: "v"(tp), "v"(tv) : "memory");
        else
          __hip_atomic_store(tp, tv, __ATOMIC_RELAXED,
                             __HIP_MEMORY_SCOPE_AGENT);
      }
    }
  }

  // final h (fp32 master copy) -> d_out
  if (c < 8) {
#pragma unroll
    for (int r = 0; r < 4; r++) {
      int b = wave * 16 + q * 4 + r;
      out[(size_t)b * NH + wg * 8 + c] = hold[r];
    }
  }
}

__global__ __launch_bounds__(256, 2)
void gru_persistent(const float* __restrict__ x,
                    const float* __restrict__ Wih,
                    const float* __restrict__ Whh,
                    const float* __restrict__ bih,
                    const float* __restrict__ bhh,
                    float* __restrict__ out,
                    unsigned char* __restrict__ ws) {
  const int bid  = blockIdx.x;   // 0..511
  const int tid  = threadIdx.x;  // 0..255
  const int wave = tid >> 6;
  const int lane = tid & 63;
  const int c    = lane & 15;
  const int q    = lane >> 4;

  const unsigned long long t0 = __builtin_amdgcn_s_memrealtime();

  unsigned long long* flags = (unsigned long long*)(ws + OFF_FLAGS);
  int* tags = (int*)(ws + OFF_TAGS);
  unsigned* hb0d = (unsigned*)(ws + OFF_HB0);
  unsigned short* xb = (unsigned short*)(ws + OFF_XB);

  __shared__ __align__(16) unsigned short trans[4][16][8];
  __shared__ int s_bad;

  const bool is_worker = (bid & 7) == 0;
  const int rank = bid >> 3;

  // ---- prologue (all 512 blocks): xb conversion split 512 ways;
  //      workers zero their own hb0 slice; block 0 zeros tags ----
  {
    const float4* x4 = (const float4*)x;
    const int total4 = NB * NT * NI / 4;   // 2,097,152
    const int nthr = 512 * 256;
    for (int i = bid * 256 + tid; i < total4; i += nthr) {
      float4 v = x4[i];
      ushort4 o;
      o.x = (unsigned short)f2b(v.x);
      o.y = (unsigned short)f2b(v.y);
      o.z = (unsigned short)f2b(v.z);
      o.w = (unsigned short)f2b(v.w);
      ((ushort4*)xb)[i] = o;
    }
    if (is_worker) hb0d[rank * 256 + tid] = 0u;  // own 1KB publish slice
    if (bid == 0) tags[tid] = 0;
  }

  __syncthreads();
  if (tid == 0)
    __hip_atomic_store(&flags[bid * 8], __builtin_amdgcn_s_memrealtime(),
                       __ATOMIC_RELEASE, __HIP_MEMORY_SCOPE_AGENT);
  if (!is_worker) return;  // frees the CU slot; all 512 flag eventually

  // ---- workers: weight fragments (overlaps other blocks' prologues) ----
  bf16x8 wh[2][16];
  bf16x8 wi[2][8];
#pragma unroll
  for (int nt = 0; nt < 2; nt++) {
    int nl = nt * 16 + c;
    bool valid = nl < 24;
    int gate = nl >> 3;
    int jj = nl & 7;
    int grow = valid ? (gate * NH + rank * 8 + jj) : 0;
#pragma unroll
    for (int kk = 0; kk < 16; kk++) {
      const float* p = Whh + (size_t)grow * NH + kk * 32 + q * 8;
      bf16x8 f;
#pragma unroll
      for (int e = 0; e < 8; e++) f[e] = valid ? f2b(p[e]) : (short)0;
      wh[nt][kk] = f;
    }
#pragma unroll
    for (int kk = 0; kk < 8; kk++) {
      const float* p = Wih + (size_t)grow * NI + kk * 32 + q * 8;
      bf16x8 f;
#pragma unroll
      for (int e = 0; e < 8; e++) f[e] = valid ? f2b(p[e]) : (short)0;
      wi[nt][kk] = f;
    }
  }

  // ---- 512-flag barrier (timestamp-gated; 2ms deadline -> degrade to
  //      R5's empirically-safe weak ordering rather than hang) ----
  if (wave == 0) {
#pragma unroll
    for (int j = 0; j < 8; j++) {
      const unsigned long long dl = t0 + 200000ull;  // ~2ms @100MHz
      while (__hip_atomic_load(&flags[(lane * 8 + j) * 8], __ATOMIC_RELAXED,
                               __HIP_MEMORY_SCOPE_AGENT) < t0) {
        if (__builtin_amdgcn_s_memrealtime() > dl) break;
        __builtin_amdgcn_s_sleep(1);
      }
    }
  }
  __syncthreads();
  __threadfence();  // acquire: fresh view of all prologue data

  // ---- coherence self-test: proves {workers share one L2} AND
  //      {buffer_inv sc0 invalidates L1} before trusting the fast path --
  if (tid == 0) s_bad = 0;
  // phase 1: arm this CU's L1/L2 with the 64 test lines (stale or not)
  if (wave == 0) {
    int v;
    const void* p = ws + OFF_TESTA + (size_t)lane * 64;
    asm volatile("global_load_dword %0, %1, off" : "=v"(v) : "v"(p));
    asm volatile("s_waitcnt vmcnt(0)" : "+v"(v)::"memory");
  }
  tsbar(ws + OFF_TSB1, rank, tid, wave, lane, t0);
  // common per-launch epoch (rank-0's phase-1 timestamp, single write)
  const unsigned ep = (unsigned)__hip_atomic_load(
      (const unsigned long long*)(ws + OFF_TSB1), __ATOMIC_RELAXED,
      __HIP_MEMORY_SCOPE_AGENT);
  // phase 2: plain-store epoch-tagged magic, drain (reaches own L2 only)
  if (tid == 0) {
    unsigned mg = (ep ^ 0x5EEDBEEFu) + (unsigned)rank * 2654435761u;
    void* p = ws + OFF_TESTA + (size_t)rank * 64;
    asm volatile("global_store_dword %0, %1, off" :: "v"(p), "v"(mg)
                 : "memory");
    asm volatile("s_waitcnt vmcnt(0)" ::: "memory");
  }
  tsbar(ws + OFF_TSB2, rank, tid, wave, lane, t0);
  // phase 3: inv L1, plain re-read all 64; any non-fresh value -> demote
  {
    int bad = 0;
    if (wave == 0) {
      asm volatile("buffer_inv sc0" ::: "memory");
      int v;
      const void* p = ws + OFF_TESTA + (size_t)lane * 64;
      asm volatile("global_load_dword %0, %1, off" : "=v"(v) : "v"(p));
      asm volatile("s_waitcnt vmcnt(0)" : "+v"(v)::"memory");
      unsigned want = (ep ^ 0x5EEDBEEFu) + (unsigned)lane * 2654435761u;
      bad = (v != (int)want);
    }
    if (bad) s_bad = 1;
    __syncthreads();
    if (s_bad && tid == 0)
      __hip_atomic_store((unsigned long long*)(ws + OFF_DEMOTE),
                         __builtin_amdgcn_s_memrealtime(), __ATOMIC_RELEASE,
                         __HIP_MEMORY_SCOPE_AGENT);
  }
  tsbar(ws + OFF_TSB3, rank, tid, wave, lane, t0);
  const bool fast =
      __hip_atomic_load((const unsigned long long*)(ws + OFF_DEMOTE),
                        __ATOMIC_RELAXED, __HIP_MEMORY_SCOPE_AGENT) < t0;

  if (fast)
    worker_body<true>(rank, tid, bih, bhh, out, ws, wh, wi, trans);
  else
    worker_body<false>(rank, tid, bih, bhh, out, ws, wh, wi, trans);
}

extern "C" void kernel_launch(void* const* d_in, const int* in_sizes, int n_in,
                              void* d_out, int out_size, void* d_ws, size_t ws_size,
                              hipStream_t stream) {
  const float* x   = (const float*)d_in[0];
  const float* Wih = (const float*)d_in[1];
  const float* Whh = (const float*)d_in[2];
  const float* bih = (const float*)d_in[3];
  const float* bhh = (const float*)d_in[4];
  float* out = (float*)d_out;
  hipLaunchKernelGGL(gru_persistent, dim3(512), dim3(256), 0, stream,
                     x, Wih, Whh, bih, bhh, out, (unsigned char*)d_ws);
}